// Round 17
// baseline (231.150 us; speedup 1.0000x reference)
//
#include <hip/hip_runtime.h>
#include <hip/hip_bf16.h>
#include <stdint.h>

// AttentiveFP readout: B=2048 graphs x (48 real + 1 virtual) nodes, D=256, H=8, DH=32, 4 steps.
// Round-17 = round-16 (FX fragment-layout x buffers) with the epilogue base fixed:
// chunk g = f*3+mi occupies elements [g*64, g*64+64) -> store base uses f*192 (was f*3).
//  - af loads: 1KB contiguous per wave-instruction.
//  - Ws-strip epilogue: graph-local contiguous 3KB chunk region fully written per epilogue.
//  - setup writes X0 fragments in a 2nd pass over nf (L3-hot after the sum pass).
// GRU fold in fused prologue (t>=1), E-phase folded attention (WGAS/WGAD), sv from Ws mi=3,
// counted-vmcnt strip pipeline, merged gates GEMM, final gru + projection.

#define NEG_SLOPE 0.2f

typedef unsigned short u16;
typedef short s16x8 __attribute__((ext_vector_type(8)));
typedef float f32x4 __attribute__((ext_vector_type(4)));
typedef float f32x2 __attribute__((ext_vector_type(2)));
typedef u16 u16x2 __attribute__((ext_vector_type(2)));
typedef u16 u16x4 __attribute__((ext_vector_type(4)));
typedef u16 u16x8 __attribute__((ext_vector_type(8)));

__device__ __forceinline__ u16 f2bf(float f) {
  union { float f; uint32_t u; } v; v.f = f;
  uint32_t r = (v.u + 0x7FFFu + ((v.u >> 16) & 1u)) >> 16;  // RNE
  return (u16)r;
}

__device__ __forceinline__ void gload_lds16(const void* g, void* l) {
  __builtin_amdgcn_global_load_lds(
      (const __attribute__((address_space(1))) void*)g,
      (__attribute__((address_space(3))) void*)l, 16, 0, 0);
}

__device__ __forceinline__ float redsum_lk(float v) {
  v += __shfl_xor(v, 16); v += __shfl_xor(v, 32);
  return v;
}
__device__ __forceinline__ float redmax_lk(float v) {
  v = fmaxf(v, __shfl_xor(v, 16)); v = fmaxf(v, __shfl_xor(v, 32));
  return v;
}
__device__ __forceinline__ float sigm(float x) { return 1.f / (1.f + expf(-x)); }

// ---------------------------------------------------------------------------
// SETUP kernel: block ranges
//   [0,2048)      prep: virtual sum -> state_0; X0 fragment-layout bf16 write
//   [2048,2160)   LDS-tiled transpose-convert: wx/wh/pw -> WXT/WHT/PRJ (64x64 tiles)
//   [2160,2224)   BP strip pack ([Wg|Ws], 32-col strips, even/odd)
//   [2224,2240)   EP: WGAS/WGAD dots, one thread per (chunk, elem)
// ---------------------------------------------------------------------------
__global__ __launch_bounds__(256)
void setup_kernel(const float* __restrict__ nf, const float* __restrict__ Wg,
                  const float* __restrict__ Ws, const float* __restrict__ wx,
                  const float* __restrict__ wh, const float* __restrict__ pw,
                  const float* __restrict__ asrc, const float* __restrict__ adst,
                  u16* __restrict__ X0, float* __restrict__ state, u16* __restrict__ GS,
                  u16* __restrict__ WXT, u16* __restrict__ WHT, u16* __restrict__ PRJ,
                  u16* __restrict__ BP, u16* __restrict__ EP) {
  __shared__ union {
    f32x4 part[4][64];        // prep
    float trn[64][65];        // transpose tile (padded)
  } sm;
  const int blk = blockIdx.x, t = threadIdx.x;

  if (blk < 2048) {
    // ---- prep pass 1: column sums -> state_0 ----
    const int b = blk, c4 = t & 63, sg = t >> 6;
    const f32x4* src = (const f32x4*)(nf + (size_t)b * 48 * 256);
    f32x4 acc = (f32x4){0.f, 0.f, 0.f, 0.f};
    for (int s = sg * 12; s < sg * 12 + 12; ++s) acc += src[(size_t)s * 64 + c4];
    sm.part[sg][c4] = acc;
    __syncthreads();
    if (t < 64) {
      f32x4 r = sm.part[0][t] + sm.part[1][t] + sm.part[2][t] + sm.part[3][t];
#pragma unroll
      for (int j = 0; j < 4; ++j) {
        int d = t * 4 + j;
        state[(size_t)b * 256 + d] = r[j];
        GS[(size_t)b * 512 + 256 + d] = f2bf(r[j]);
      }
    }
    // ---- prep pass 2: X0 fragment chunks (nf is L2/L3-hot from pass 1) ----
#pragma unroll
    for (int q = 0; q < 6; ++q) {
      const int c = q * 256 + t;                 // element index 0..1535 (= g*64 + l)
      const int l = c & 63, g = c >> 6;          // g = kc*3+mi
      const int mi = g % 3, kc = g / 3;
      const float* s = nf + ((size_t)b * 48 + mi * 16 + (l & 15)) * 256 + kc * 32 +
                       ((l >> 4) & 3) * 8;
      f32x4 u0 = *(const f32x4*)s, u1 = *(const f32x4*)(s + 4);
      u16x8 o;
#pragma unroll
      for (int e = 0; e < 4; ++e) { o[e] = f2bf(u0[e]); o[4 + e] = f2bf(u1[e]); }
      *(u16x8*)(X0 + ((size_t)b * 1536 + c) * 8) = o;
    }
  } else if (blk < 2160) {
    // ---- transpose tile: dst[N][256] bf16 <- src[K=256][N] f32, 64x64 tiles ----
    int tt = blk - 2048;
    const float* src; u16* dst; int N, kt, nt;
    if (tt < 48)       { src = wx; dst = WXT; N = 768; kt = tt & 3; nt = tt >> 2; }
    else if (tt < 96)  { tt -= 48; src = wh; dst = WHT; N = 768; kt = tt & 3; nt = tt >> 2; }
    else               { tt -= 96; src = pw; dst = PRJ; N = 256; kt = tt & 3; nt = tt >> 2; }
    const int k0 = kt * 64, n0 = nt * 64;
    const int c = t & 63, r4 = t >> 6;
#pragma unroll
    for (int i = 0; i < 16; ++i) {
      const int kl = i * 4 + r4;
      sm.trn[c][kl] = src[(size_t)(k0 + kl) * N + n0 + c];  // coalesced read
    }
    __syncthreads();
    const int nl = t >> 2, kc16 = (t & 3) * 16;
    u16x8 o0, o1;
#pragma unroll
    for (int e = 0; e < 8; ++e) {
      o0[e] = f2bf(sm.trn[nl][kc16 + e]);
      o1[e] = f2bf(sm.trn[nl][kc16 + 8 + e]);
    }
    u16* dp = dst + (size_t)(n0 + nl) * 256 + k0 + kc16;
    *(u16x8*)dp = o0;
    *(u16x8*)(dp + 8) = o1;
  } else if (blk < 2224) {
    // ---- BP: [Wg | Ws] 32-col strips, even/odd within strip ----
    int cch = (blk - 2160) * 256 + t;  // 16384 chunks
    int l = cch & 63, ni = (cch >> 6) & 1, kc = (cch >> 7) & 7, s = cch >> 10;
    int n = s * 32 + ((l & 15) << 1) + ni;
    int k0 = kc * 32 + (l >> 4) * 8;
    const float* W = (n < 256) ? Wg : Ws;
    int nn = n & 255;
    u16x8 o;
#pragma unroll
    for (int e = 0; e < 8; ++e) o[e] = f2bf(W[(size_t)(k0 + e) * 256 + nn]);
    *(u16x8*)(BP + (size_t)cch * 8) = o;
  } else {
    // ---- EP: cols 0-7 = WGAS (Wg@asrc), 8-15 = WGAD (Wg@adst); thread=(chunk,elem) ----
    int idx = (blk - 2224) * 256 + t;  // 4096 = 512 chunks x 8 elems
    int cch = idx >> 3, e = idx & 7;
    int l = cch & 63, kc = cch >> 6;
    int hh = l & 15, h = hh & 7;
    int k0 = kc * 32 + (l >> 4) * 8;
    const float* av = (hh < 8) ? asrc : adst;
    float s = 0.f;
#pragma unroll
    for (int j = 0; j < 32; ++j)
      s += Wg[(size_t)(k0 + e) * 256 + h * 32 + j] * av[h * 32 + j];
    EP[(size_t)cch * 8 + e] = f2bf(s);
  }
}

// ---------------------------------------------------------------------------
// FUSED step: 1024 blocks x 128 threads (2 waves); wave w owns graph blockIdx*2+w.
// X / Xn in FRAGMENT layout: per graph, element (g*64+l) of 16B, g = kc*3+mi.
// GRUF: compute state_t = GRU(G1,G2,ST) in prologue. LAST: Ws strips only mi=3 (sv).
// ---------------------------------------------------------------------------
template<bool GRUF, bool LAST>
__global__ __launch_bounds__(128, 2)
void fused_step(const u16* __restrict__ X, const u16* __restrict__ BP,
                const u16* __restrict__ EP, u16* __restrict__ GS,
                u16* __restrict__ Xn,
                const float* __restrict__ G1, const float* __restrict__ G2,
                const float* __restrict__ bx, const float* __restrict__ bh,
                float* __restrict__ ST) {
  __shared__ u16 ldsB[2][8192];        // 2 x 16KB strip buffers (fragment-major)
  __shared__ float alphaL[2][8][48];   // per-wave normalized attention weights
  __shared__ u16 stH[2][256];          // per-wave bf16 state row (GRU fold)
  const int tid = threadIdx.x;
  const int w = tid >> 6, l = tid & 63, lr = l & 15, lk = l >> 4;
  const int b = blockIdx.x * 2 + w;
  const u16* FXg = X + (size_t)b * 1536 * 8;   // fragment chunks of this graph
  const u16* Sg = GS + (size_t)b * 512 + 256;  // state row (bf16), non-GRUF path

#define STAGE(S, BUF)                                                          \
  {                                                                            \
    _Pragma("unroll") for (int i_ = 0; i_ < 8; ++i_)                           \
        gload_lds16(BP + ((size_t)(S)*1024 + i_ * 128 + tid) * 8,              \
                    &ldsB[BUF][(i_ * 128 + w * 64) * 8]);                      \
  }

  // ---- prologue: x A-fragments (coalesced 1KB loads from fragment layout) ----
  s16x8 af[8][4];
#pragma unroll
  for (int kc = 0; kc < 8; ++kc)
#pragma unroll
    for (int mi = 0; mi < 3; ++mi)
      af[kc][mi] = *(const s16x8*)(FXg + ((size_t)(kc * 3 + mi) * 64 + l) * 8);

  // ---- state row: GRU fold (t>=1) or load from GS (t==0) ----
  if (GRUF) {
    const float* g1 = G1 + (size_t)b * 768;
    const float* g2 = G2 + (size_t)b * 768;
    const int d0 = l * 4;
    f32x4 xz = *(const f32x4*)(g1 + d0);
    f32x4 xr = *(const f32x4*)(g1 + 256 + d0);
    f32x4 xh = *(const f32x4*)(g1 + 512 + d0);
    f32x4 hz = *(const f32x4*)(g2 + d0);
    f32x4 hr = *(const f32x4*)(g2 + 256 + d0);
    f32x4 hh = *(const f32x4*)(g2 + 512 + d0);
    f32x4 bxz = *(const f32x4*)(bx + d0);
    f32x4 bxr = *(const f32x4*)(bx + 256 + d0);
    f32x4 bxh = *(const f32x4*)(bx + 512 + d0);
    f32x4 bhz = *(const f32x4*)(bh + d0);
    f32x4 bhr = *(const f32x4*)(bh + 256 + d0);
    f32x4 bhh = *(const f32x4*)(bh + 512 + d0);
    f32x4 h0 = *(const f32x4*)(ST + (size_t)b * 256 + d0);
    f32x4 sn;
    u16x4 snh;
#pragma unroll
    for (int j = 0; j < 4; ++j) {
      float z = sigm(xz[j] + bxz[j] + hz[j] + bhz[j]);
      float r = sigm(xr[j] + bxr[j] + hr[j] + bhr[j]);
      float n = tanhf(xh[j] + bxh[j] + r * (hh[j] + bhh[j]));
      sn[j] = z * h0[j] + (1.f - z) * n;
      snh[j] = f2bf(sn[j]);
    }
    *(f32x4*)(ST + (size_t)b * 256 + d0) = sn;          // state_t f32
    *(u16x4*)(GS + (size_t)b * 512 + 256 + d0) = snh;   // state_t bf16 (gates kernel)
    *(u16x4*)(&stH[w][d0]) = snh;                       // LDS for A-fragment build
    asm volatile("s_waitcnt lgkmcnt(0)" ::: "memory");
#pragma unroll
    for (int kc = 0; kc < 8; ++kc)
      af[kc][3] = *(const s16x8*)&stH[w][kc * 32 + lk * 8];
  } else {
#pragma unroll
    for (int kc = 0; kc < 8; ++kc)
      af[kc][3] = *(const s16x8*)(Sg + kc * 32 + lk * 8);
  }

  s16x8 be[8];
#pragma unroll
  for (int kc = 0; kc < 8; ++kc)
    be[kc] = *(const s16x8*)(EP + ((size_t)kc * 64 + l) * 8);

  asm volatile("s_waitcnt vmcnt(0)" ::: "memory");  // vmcnt domain now stage/store-only
  STAGE(8, 0)  // first processed strip: Ws window 0 (BP strip 8)

  // ---- E-phase: 32 MFMA -> e_src (rows 0-47, cols 0-7) + e_dst (cols 8-15) ----
  {
    f32x4 ae[4];
#pragma unroll
    for (int mi = 0; mi < 4; ++mi) ae[mi] = (f32x4){0.f, 0.f, 0.f, 0.f};
#pragma unroll
    for (int kc = 0; kc < 8; ++kc)
#pragma unroll
      for (int mi = 0; mi < 4; ++mi)
        ae[mi] = __builtin_amdgcn_mfma_f32_16x16x32_bf16(af[kc][mi], be[kc], ae[mi], 0, 0, 0);

    // e_dst[h] lives on lane (lr'=8+h) as ae[3][*] (all rows equal).
    const float edv = __shfl(ae[3][0], 8 + lr);  // valid for lanes lr<8

    if (lr < 8) {  // lane lr owns head lr for its lk-row-group
      float ev[3][4];
      float m = -1e30f;
#pragma unroll
      for (int mi = 0; mi < 3; ++mi)
#pragma unroll
        for (int j = 0; j < 4; ++j) {
          float v = ae[mi][j] + edv;
          v = (v > 0.f) ? v : NEG_SLOPE * v;  // leaky_relu
          ev[mi][j] = v;
          m = fmaxf(m, v);
        }
      m = redmax_lk(m);  // max over all 48 nodes
      float sm = 0.f;
#pragma unroll
      for (int mi = 0; mi < 3; ++mi)
#pragma unroll
        for (int j = 0; j < 4; ++j) {
          float ex = expf(ev[mi][j] - m);
          ev[mi][j] = ex; sm += ex;
        }
      sm = redsum_lk(sm);
      const float inv = 1.f / sm;
#pragma unroll
      for (int mi = 0; mi < 3; ++mi)
#pragma unroll
        for (int j = 0; j < 4; ++j)
          alphaL[w][lr][mi * 16 + lk * 4 + j] = ev[mi][j] * inv;
    }
  }

  f32x2 svA[8];  // sv pairs (cols 2lr, 2lr+1 of each head window), from Ws mi=3

  // ---- strip pipeline: Ws strips (f=0..7, BP 8..15) then Wg strips (f=8..15, BP 0..7) ----
#pragma unroll
  for (int f = 0; f < 16; ++f) {
    if (f == 0)       { asm volatile("s_waitcnt vmcnt(0)" ::: "memory"); }
    else if (f <= 8)  {
      if (LAST)       { asm volatile("s_waitcnt vmcnt(0)" ::: "memory"); }
      else            { asm volatile("s_waitcnt vmcnt(12)" ::: "memory"); }
    } else            { asm volatile("s_waitcnt vmcnt(1)" ::: "memory"); }
    __builtin_amdgcn_s_barrier();
    if (f + 1 < 16) {
      const int ns = (f + 1 < 8) ? (9 + f) : (f + 1 - 8);
      STAGE(ns, (f + 1) & 1)
    }

    const u16* bufB = ldsB[f & 1];

    if (f < 8) {
      // ---- Ws window u=f: x@Ws (mi 0-2, skipped in LAST) + sv (mi 3) ----
      f32x4 acc[4][2];
#pragma unroll
      for (int mi = 0; mi < 4; ++mi)
#pragma unroll
        for (int ni = 0; ni < 2; ++ni) acc[mi][ni] = (f32x4){0.f, 0.f, 0.f, 0.f};
#pragma unroll
      for (int kc = 0; kc < 8; ++kc) {
        s16x8 bfr[2];
#pragma unroll
        for (int ni = 0; ni < 2; ++ni)
          bfr[ni] = *(const s16x8*)&bufB[((kc * 2 + ni) * 64 + l) * 8];
        if (!LAST) {
#pragma unroll
          for (int mi = 0; mi < 3; ++mi)
#pragma unroll
            for (int ni = 0; ni < 2; ++ni)
              acc[mi][ni] = __builtin_amdgcn_mfma_f32_16x16x32_bf16(
                  af[kc][mi], bfr[ni], acc[mi][ni], 0, 0, 0);
        }
#pragma unroll
        for (int ni = 0; ni < 2; ++ni)
          acc[3][ni] = __builtin_amdgcn_mfma_f32_16x16x32_bf16(
              af[kc][3], bfr[ni], acc[3][ni], 0, 0, 0);
      }
      svA[f] = (f32x2){acc[3][0][0], acc[3][1][0]};  // sv (rows all equal)
      if (!LAST) {
        // fragment-layout stores: strip f produces chunks g = f*3+mi, which start at
        // element index g*64 -> base element f*192. Value (row,col) -> lane
        // l' = (lr>>2)*16 + lk*4 + j, elem e = (lr&3)*2 + ni; whole 3KB region written
        // within this epilogue -> full-line HBM writes.
        u16* cb = Xn + ((size_t)b * 1536 + (size_t)f * 192) * 8;
        const int loff = ((lr >> 2) * 16 + lk * 4) * 8 + (lr & 3) * 2;
#pragma unroll
        for (int mi = 0; mi < 3; ++mi)
#pragma unroll
          for (int j = 0; j < 4; ++j) {
            u16x2 o = {f2bf(fmaxf(acc[mi][0][j], 0.f)),
                       f2bf(fmaxf(acc[mi][1][j], 0.f))};
            *(u16x2*)(cb + (size_t)mi * 512 + loff + j * 8) = o;
          }
      }
    } else {
      // ---- Wg head h=f-8: msg via alpha table, g0 = relu(msg+sv), 1 u16x2 store ----
      const int h = f - 8;
      f32x4 acc[3][2];
#pragma unroll
      for (int mi = 0; mi < 3; ++mi)
#pragma unroll
        for (int ni = 0; ni < 2; ++ni) acc[mi][ni] = (f32x4){0.f, 0.f, 0.f, 0.f};
#pragma unroll
      for (int kc = 0; kc < 8; ++kc) {
        s16x8 bfr[2];
#pragma unroll
        for (int ni = 0; ni < 2; ++ni)
          bfr[ni] = *(const s16x8*)&bufB[((kc * 2 + ni) * 64 + l) * 8];
#pragma unroll
        for (int mi = 0; mi < 3; ++mi)
#pragma unroll
          for (int ni = 0; ni < 2; ++ni)
            acc[mi][ni] = __builtin_amdgcn_mfma_f32_16x16x32_bf16(
                af[kc][mi], bfr[ni], acc[mi][ni], 0, 0, 0);
      }
      float mmE = 0.f, mmO = 0.f;
#pragma unroll
      for (int mi = 0; mi < 3; ++mi)
#pragma unroll
        for (int j = 0; j < 4; ++j) {
          const float a = alphaL[w][h][mi * 16 + lk * 4 + j];
          mmE += a * acc[mi][0][j];
          mmO += a * acc[mi][1][j];
        }
      mmE = redsum_lk(mmE);
      mmO = redsum_lk(mmO);
      if (lk == 0) {
        u16x2 o = {f2bf(fmaxf(mmE + svA[h][0], 0.f)),
                   f2bf(fmaxf(mmO + svA[h][1], 0.f))};
        *(u16x2*)(GS + (size_t)b * 512 + h * 32 + 2 * lr) = o;
      }
    }
  }
#undef STAGE
}

// ---------------------------------------------------------------------------
// Generic bf16 GEMM: C[M,N] = A[M,K=256] * Bt[N,K=256]^T, 128x128, pipelined.
// EPI 2 = f32 + bias (projection).
// ---------------------------------------------------------------------------
template<int EPI>
__global__ __launch_bounds__(256)
void gemm_bt(const u16* __restrict__ A, int lda,
             const u16* __restrict__ Bt,
             float* __restrict__ Cf, int ldc, const float* __restrict__ bias) {
  __shared__ u16 ldsA[2][2 * 128 * 32];
  __shared__ u16 ldsB[2][2 * 128 * 32];
  const int tid = threadIdx.x;
  const int w = tid >> 6, l = tid & 63;
  const int wr = w >> 1, wc = w & 1;
  const int lr = l & 15, lk = l >> 4;
  const int sxor = (lr >> 1) & 3;
  const int m0 = blockIdx.x * 128, n0 = blockIdx.y * 128;

#define STAGE_AB(KT, BUF)                                                      \
  {                                                                            \
    const u16* Ag = A + (size_t)m0 * lda + (KT)*64;                            \
    const u16* Bg = Bt + (size_t)n0 * 256 + (KT)*64;                           \
    _Pragma("unroll") for (int i = 0; i < 4; ++i) {                            \
      int q = i * 256 + tid;                                                   \
      int h2 = q >> 9, r = (q >> 2) & 127, c4 = q & 3;                         \
      int c4s = c4 ^ ((r >> 1) & 3);                                           \
      gload_lds16(Ag + (size_t)r * lda + h2 * 32 + c4s * 8,                    \
                  &ldsA[BUF][(i * 256 + w * 64) * 8]);                         \
      gload_lds16(Bg + (size_t)r * 256 + h2 * 32 + c4s * 8,                    \
                  &ldsB[BUF][(i * 256 + w * 64) * 8]);                         \
    }                                                                          \
  }

  f32x4 acc[4][4];
#pragma unroll
  for (int i = 0; i < 4; ++i)
#pragma unroll
    for (int j = 0; j < 4; ++j) acc[i][j] = (f32x4){0.f, 0.f, 0.f, 0.f};

  STAGE_AB(0, 0)
#pragma unroll
  for (int kt = 0; kt < 4; ++kt) {
    __syncthreads();
    if (kt < 3) STAGE_AB(kt + 1, (kt + 1) & 1)
    const u16* bA = ldsA[kt & 1];
    const u16* bB = ldsB[kt & 1];
#pragma unroll
    for (int hh = 0; hh < 2; ++hh) {
      s16x8 af[4], bfr[4];
#pragma unroll
      for (int mi = 0; mi < 4; ++mi)
        af[mi] = *(const s16x8*)&bA[(hh * 128 + wr * 64 + mi * 16 + lr) * 32 +
                                    (lk ^ sxor) * 8];
#pragma unroll
      for (int ni = 0; ni < 4; ++ni)
        bfr[ni] = *(const s16x8*)&bB[(hh * 128 + wc * 64 + ni * 16 + lr) * 32 +
                                     (lk ^ sxor) * 8];
#pragma unroll
      for (int mi = 0; mi < 4; ++mi)
#pragma unroll
        for (int ni = 0; ni < 4; ++ni)
          acc[mi][ni] = __builtin_amdgcn_mfma_f32_16x16x32_bf16(af[mi], bfr[ni],
                                                                acc[mi][ni], 0, 0, 0);
    }
  }
#undef STAGE_AB

#pragma unroll
  for (int mi = 0; mi < 4; ++mi) {
#pragma unroll
    for (int ni = 0; ni < 4; ++ni) {
      f32x4 v = acc[mi][ni];
      int r = m0 + wr * 64 + mi * 16 + lk * 4;
      int c = n0 + wc * 64 + ni * 16 + lr;
#pragma unroll
      for (int j = 0; j < 4; ++j) {
        float fv = v[j];
        if (EPI == 0) Cf[(size_t)(r + j) * ldc + c] = fv;
        else          Cf[(size_t)(r + j) * ldc + c] = fv + bias[c];
      }
    }
  }
}

// Merged GRU-gate GEMM: blockIdx.y<6 -> G1 = g0@wx ; else G2 = state@wh. Pipelined.
__global__ __launch_bounds__(256)
void gemm_gates(const u16* __restrict__ GS, const u16* __restrict__ WXT,
                const u16* __restrict__ WHT, float* __restrict__ G1,
                float* __restrict__ G2) {
  __shared__ u16 ldsA[2][2 * 128 * 32];
  __shared__ u16 ldsB[2][2 * 128 * 32];
  const bool second = blockIdx.y >= 6;
  const u16* A = GS + (second ? 256 : 0);
  const u16* Bt = second ? WHT : WXT;
  float* Cf = second ? G2 : G1;
  const int n0 = (second ? blockIdx.y - 6 : blockIdx.y) * 128;
  const int m0 = blockIdx.x * 128;
  const int tid = threadIdx.x;
  const int w = tid >> 6, l = tid & 63;
  const int wr = w >> 1, wc = w & 1;
  const int lr = l & 15, lk = l >> 4;
  const int sxor = (lr >> 1) & 3;

#define STAGE_AB(KT, BUF)                                                      \
  {                                                                            \
    const u16* Ag = A + (size_t)m0 * 512 + (KT)*64;                            \
    const u16* Bg = Bt + (size_t)n0 * 256 + (KT)*64;                           \
    _Pragma("unroll") for (int i = 0; i < 4; ++i) {                            \
      int q = i * 256 + tid;                                                   \
      int h2 = q >> 9, r = (q >> 2) & 127, c4 = q & 3;                         \
      int c4s = c4 ^ ((r >> 1) & 3);                                           \
      gload_lds16(Ag + (size_t)r * 512 + h2 * 32 + c4s * 8,                    \
                  &ldsA[BUF][(i * 256 + w * 64) * 8]);                         \
      gload_lds16(Bg + (size_t)r * 256 + h2 * 32 + c4s * 8,                    \
                  &ldsB[BUF][(i * 256 + w * 64) * 8]);                         \
    }                                                                          \
  }

  f32x4 acc[4][4];
#pragma unroll
  for (int i = 0; i < 4; ++i)
#pragma unroll
    for (int j = 0; j < 4; ++j) acc[i][j] = (f32x4){0.f, 0.f, 0.f, 0.f};

  STAGE_AB(0, 0)
#pragma unroll
  for (int kt = 0; kt < 4; ++kt) {
    __syncthreads();
    if (kt < 3) STAGE_AB(kt + 1, (kt + 1) & 1)
    const u16* bA = ldsA[kt & 1];
    const u16* bB = ldsB[kt & 1];
#pragma unroll
    for (int hh = 0; hh < 2; ++hh) {
      s16x8 af[4], bfr[4];
#pragma unroll
      for (int mi = 0; mi < 4; ++mi)
        af[mi] = *(const s16x8*)&bA[(hh * 128 + wr * 64 + mi * 16 + lr) * 32 +
                                    (lk ^ sxor) * 8];
#pragma unroll
      for (int ni = 0; ni < 4; ++ni)
        bfr[ni] = *(const s16x8*)&bB[(hh * 128 + wc * 64 + ni * 16 + lr) * 32 +
                                     (lk ^ sxor) * 8];
#pragma unroll
      for (int mi = 0; mi < 4; ++mi)
#pragma unroll
        for (int ni = 0; ni < 4; ++ni)
          acc[mi][ni] = __builtin_amdgcn_mfma_f32_16x16x32_bf16(af[mi], bfr[ni],
                                                                acc[mi][ni], 0, 0, 0);
    }
  }
#undef STAGE_AB

#pragma unroll
  for (int mi = 0; mi < 4; ++mi) {
#pragma unroll
    for (int ni = 0; ni < 4; ++ni) {
      f32x4 v = acc[mi][ni];
      int r = m0 + wr * 64 + mi * 16 + lk * 4;
      int c = n0 + wc * 64 + ni * 16 + lr;
#pragma unroll
      for (int j = 0; j < 4; ++j)
        Cf[(size_t)(r + j) * 768 + c] = v[j];
    }
  }
}

// GRU elementwise (final step only: state_4 for projection)
__global__ void gru_kernel(const float* __restrict__ G1, const float* __restrict__ G2,
                           const float* __restrict__ bx, const float* __restrict__ bh,
                           float* __restrict__ state, u16* __restrict__ GS) {
  const int b = blockIdx.x, d = threadIdx.x;
  const float* g1 = G1 + (size_t)b * 768;
  const float* g2 = G2 + (size_t)b * 768;
  float xz = g1[d] + bx[d], xr = g1[256 + d] + bx[256 + d], xh = g1[512 + d] + bx[512 + d];
  float hz = g2[d] + bh[d], hr = g2[256 + d] + bh[256 + d], hh2 = g2[512 + d] + bh[512 + d];
  float z = sigm(xz + hz);
  float r = sigm(xr + hr);
  float n = tanhf(xh + r * hh2);
  float h0 = state[b * 256 + d];
  float sn = z * h0 + (1.f - z) * n;
  state[b * 256 + d] = sn;
  GS[(size_t)b * 512 + 256 + d] = f2bf(sn);
}

extern "C" void kernel_launch(void* const* d_in, const int* in_sizes, int n_in,
                              void* d_out, int out_size, void* d_ws, size_t ws_size,
                              hipStream_t stream) {
  const float* nf  = (const float*)d_in[0];
  const float* Wg  = (const float*)d_in[2];
  const float* Ws  = (const float*)d_in[3];
  const float* asr = (const float*)d_in[4];
  const float* ads = (const float*)d_in[5];
  const float* wx  = (const float*)d_in[6];
  const float* wh  = (const float*)d_in[7];
  const float* bx  = (const float*)d_in[8];
  const float* bh  = (const float*)d_in[9];
  const float* pw  = (const float*)d_in[10];
  const float* pb  = (const float*)d_in[11];
  float* out = (float*)d_out;

  char* p = (char*)d_ws;
  size_t off = 0;
  auto alloc = [&](size_t bytes) { char* r = p + off; off += (bytes + 255) & ~255ULL; return r; };
  u16* WXT   = (u16*)alloc(768 * 256 * 2);
  u16* WHT   = (u16*)alloc(768 * 256 * 2);
  u16* PRJ   = (u16*)alloc(256 * 256 * 2);
  u16* BP    = (u16*)alloc(512 * 256 * 2);            // [Wg|Ws] 32-col strip pack
  u16* EP    = (u16*)alloc(512 * 8 * 2);              // [WGAS|WGAD] fragment pack
  u16* X0    = (u16*)alloc((size_t)2048 * 1536 * 16); // fragment-layout x (24KB/graph)
  u16* X1    = (u16*)alloc((size_t)2048 * 1536 * 16);
  float* G1   = (float*)alloc((size_t)2048 * 768 * 4);
  float* G2   = (float*)alloc((size_t)2048 * 768 * 4);
  u16* GS     = (u16*)alloc((size_t)2048 * 512 * 2);  // [g0 | state] bf16
  float* ST   = (float*)alloc((size_t)2048 * 256 * 4);

  // setup: prep + all weight packing in one launch
  setup_kernel<<<2240, 256, 0, stream>>>(nf, Wg, Ws, wx, wh, pw, asr, ads,
                                         X0, ST, GS, WXT, WHT, PRJ, BP, EP);

  // t=0: no GRU fold (state_0 from setup)
  fused_step<false, false><<<1024, 128, 0, stream>>>(X0, BP, EP, GS, X1,
                                                     G1, G2, bx, bh, ST);
  gemm_gates<<<dim3(16, 12), 256, 0, stream>>>(GS, WXT, WHT, G1, G2);
  // t=1
  fused_step<true, false><<<1024, 128, 0, stream>>>(X1, BP, EP, GS, X0,
                                                    G1, G2, bx, bh, ST);
  gemm_gates<<<dim3(16, 12), 256, 0, stream>>>(GS, WXT, WHT, G1, G2);
  // t=2
  fused_step<true, false><<<1024, 128, 0, stream>>>(X0, BP, EP, GS, X1,
                                                    G1, G2, bx, bh, ST);
  gemm_gates<<<dim3(16, 12), 256, 0, stream>>>(GS, WXT, WHT, G1, G2);
  // t=3 (LAST: Ws strips compute only sv; no Xn)
  fused_step<true, true><<<1024, 128, 0, stream>>>(X1, BP, EP, GS, nullptr,
                                                   G1, G2, bx, bh, ST);
  gemm_gates<<<dim3(16, 12), 256, 0, stream>>>(GS, WXT, WHT, G1, G2);
  // final GRU -> state_4, then projection
  gru_kernel<<<2048, 256, 0, stream>>>(G1, G2, bx, bh, ST, GS);
  gemm_bt<2><<<dim3(16, 2), 256, 0, stream>>>(GS + 256, 512, PRJ, out, 256, pb);
}

// Round 18
// 204.066 us; speedup vs baseline: 1.1327x; 1.1327x over previous
//
#include <hip/hip_runtime.h>
#include <hip/hip_bf16.h>
#include <stdint.h>

// AttentiveFP readout: B=2048 graphs x (48 real + 1 virtual) nodes, D=256, H=8, DH=32, 4 steps.
// Round-18 = round-15 (best, 212.7us; row-major X) + NF-direct t=0:
//  - fused_step<NF=true> reads nf (f32) directly, converts A-fragments on load, and
//    computes state_0 = column-sum in-register (redsum_lr butterfly lands it pre-duplicated
//    in the af[kc][3] fragment shape). lr==0 lanes write ST (f32) + GS state row (bf16).
//  - setup kernel shrinks to weight packing only (192 blocks): X0 buffer, prep pass, and
//    its 96MB nf read are deleted. First X buffer is written by fused t=0's Ws strips.
// GRU fold in fused prologue (t>=1), E-phase folded attention (WGAS/WGAD), sv from Ws mi=3,
// counted-vmcnt strip pipeline, merged gates GEMM, final gru + projection.

#define NEG_SLOPE 0.2f

typedef unsigned short u16;
typedef short s16x8 __attribute__((ext_vector_type(8)));
typedef float f32x4 __attribute__((ext_vector_type(4)));
typedef float f32x2 __attribute__((ext_vector_type(2)));
typedef u16 u16x2 __attribute__((ext_vector_type(2)));
typedef u16 u16x4 __attribute__((ext_vector_type(4)));
typedef u16 u16x8 __attribute__((ext_vector_type(8)));

__device__ __forceinline__ u16 f2bf(float f) {
  union { float f; uint32_t u; } v; v.f = f;
  uint32_t r = (v.u + 0x7FFFu + ((v.u >> 16) & 1u)) >> 16;  // RNE
  return (u16)r;
}

__device__ __forceinline__ void gload_lds16(const void* g, void* l) {
  __builtin_amdgcn_global_load_lds(
      (const __attribute__((address_space(1))) void*)g,
      (__attribute__((address_space(3))) void*)l, 16, 0, 0);
}

__device__ __forceinline__ float redsum_lr(float v) {
  v += __shfl_xor(v, 1); v += __shfl_xor(v, 2);
  v += __shfl_xor(v, 4); v += __shfl_xor(v, 8);
  return v;
}
__device__ __forceinline__ float redsum_lk(float v) {
  v += __shfl_xor(v, 16); v += __shfl_xor(v, 32);
  return v;
}
__device__ __forceinline__ float redmax_lk(float v) {
  v = fmaxf(v, __shfl_xor(v, 16)); v = fmaxf(v, __shfl_xor(v, 32));
  return v;
}
__device__ __forceinline__ float sigm(float x) { return 1.f / (1.f + expf(-x)); }

// ---------------------------------------------------------------------------
// SETUP kernel (weight packing only): block ranges
//   [0,112)    LDS-tiled transpose-convert: wx/wh/pw -> WXT/WHT/PRJ (64x64 tiles)
//   [112,176)  BP strip pack ([Wg|Ws], 32-col strips, even/odd)
//   [176,192)  EP: WGAS/WGAD dots, one thread per (chunk, elem)
// ---------------------------------------------------------------------------
__global__ __launch_bounds__(256)
void setup_kernel(const float* __restrict__ Wg, const float* __restrict__ Ws,
                  const float* __restrict__ wx, const float* __restrict__ wh,
                  const float* __restrict__ pw, const float* __restrict__ asrc,
                  const float* __restrict__ adst,
                  u16* __restrict__ WXT, u16* __restrict__ WHT, u16* __restrict__ PRJ,
                  u16* __restrict__ BP, u16* __restrict__ EP) {
  __shared__ float trn[64][65];
  const int blk = blockIdx.x, t = threadIdx.x;

  if (blk < 112) {
    // ---- transpose tile: dst[N][256] bf16 <- src[K=256][N] f32, 64x64 tiles ----
    int tt = blk;
    const float* src; u16* dst; int N, kt, nt;
    if (tt < 48)       { src = wx; dst = WXT; N = 768; kt = tt & 3; nt = tt >> 2; }
    else if (tt < 96)  { tt -= 48; src = wh; dst = WHT; N = 768; kt = tt & 3; nt = tt >> 2; }
    else               { tt -= 96; src = pw; dst = PRJ; N = 256; kt = tt & 3; nt = tt >> 2; }
    const int k0 = kt * 64, n0 = nt * 64;
    const int c = t & 63, r4 = t >> 6;
#pragma unroll
    for (int i = 0; i < 16; ++i) {
      const int kl = i * 4 + r4;
      trn[c][kl] = src[(size_t)(k0 + kl) * N + n0 + c];  // coalesced read
    }
    __syncthreads();
    const int nl = t >> 2, kc16 = (t & 3) * 16;
    u16x8 o0, o1;
#pragma unroll
    for (int e = 0; e < 8; ++e) {
      o0[e] = f2bf(trn[nl][kc16 + e]);
      o1[e] = f2bf(trn[nl][kc16 + 8 + e]);
    }
    u16* dp = dst + (size_t)(n0 + nl) * 256 + k0 + kc16;
    *(u16x8*)dp = o0;
    *(u16x8*)(dp + 8) = o1;
  } else if (blk < 176) {
    // ---- BP: [Wg | Ws] 32-col strips, even/odd within strip ----
    int cch = (blk - 112) * 256 + t;  // 16384 chunks
    int l = cch & 63, ni = (cch >> 6) & 1, kc = (cch >> 7) & 7, s = cch >> 10;
    int n = s * 32 + ((l & 15) << 1) + ni;
    int k0 = kc * 32 + (l >> 4) * 8;
    const float* W = (n < 256) ? Wg : Ws;
    int nn = n & 255;
    u16x8 o;
#pragma unroll
    for (int e = 0; e < 8; ++e) o[e] = f2bf(W[(size_t)(k0 + e) * 256 + nn]);
    *(u16x8*)(BP + (size_t)cch * 8) = o;
  } else {
    // ---- EP: cols 0-7 = WGAS (Wg@asrc), 8-15 = WGAD (Wg@adst); thread=(chunk,elem) ----
    int idx = (blk - 176) * 256 + t;  // 4096 = 512 chunks x 8 elems
    int cch = idx >> 3, e = idx & 7;
    int l = cch & 63, kc = cch >> 6;
    int hh = l & 15, h = hh & 7;
    int k0 = kc * 32 + (l >> 4) * 8;
    const float* av = (hh < 8) ? asrc : adst;
    float s = 0.f;
#pragma unroll
    for (int j = 0; j < 32; ++j)
      s += Wg[(size_t)(k0 + e) * 256 + h * 32 + j] * av[h * 32 + j];
    EP[(size_t)cch * 8 + e] = f2bf(s);
  }
}

// ---------------------------------------------------------------------------
// FUSED step: 1024 blocks x 128 threads (2 waves); wave w owns graph blockIdx*2+w.
// NF: read A from nf (f32) and compute state_0 in-register (t=0).
// GRUF: compute state_t = GRU(G1,G2,ST) in prologue (t>=1).
// LAST: Ws strips compute only mi=3 (sv); no Xn write (t=3).
// ---------------------------------------------------------------------------
template<bool GRUF, bool LAST, bool NF>
__global__ __launch_bounds__(128, 2)
void fused_step(const u16* __restrict__ X, const float* __restrict__ NFP,
                const u16* __restrict__ BP, const u16* __restrict__ EP,
                u16* __restrict__ GS, u16* __restrict__ Xn,
                const float* __restrict__ G1, const float* __restrict__ G2,
                const float* __restrict__ bx, const float* __restrict__ bh,
                float* __restrict__ ST) {
  __shared__ u16 ldsB[2][8192];        // 2 x 16KB strip buffers (fragment-major)
  __shared__ float alphaL[2][8][48];   // per-wave normalized attention weights
  __shared__ u16 stH[2][256];          // per-wave bf16 state row (GRU fold)
  const int tid = threadIdx.x;
  const int w = tid >> 6, l = tid & 63, lr = l & 15, lk = l >> 4;
  const int b = blockIdx.x * 2 + w;
  const u16* Xg = X + (size_t)b * 48 * 256;
  const u16* Sg = GS + (size_t)b * 512 + 256;  // state row (bf16), non-GRUF/non-NF path

#define STAGE(S, BUF)                                                          \
  {                                                                            \
    _Pragma("unroll") for (int i_ = 0; i_ < 8; ++i_)                           \
        gload_lds16(BP + ((size_t)(S)*1024 + i_ * 128 + tid) * 8,              \
                    &ldsB[BUF][(i_ * 128 + w * 64) * 8]);                      \
  }

  s16x8 af[8][4];

  if (NF) {
    // ---- A from nf (f32) + state_0 = column sum, all in one pass ----
#pragma unroll
    for (int kc = 0; kc < 8; ++kc) {
      float ps[8] = {0.f, 0.f, 0.f, 0.f, 0.f, 0.f, 0.f, 0.f};
#pragma unroll
      for (int mi = 0; mi < 3; ++mi) {
        const float* s = NFP + ((size_t)b * 48 + mi * 16 + lr) * 256 + kc * 32 + lk * 8;
        f32x4 u0 = *(const f32x4*)s, u1 = *(const f32x4*)(s + 4);
        s16x8 o;
#pragma unroll
        for (int e = 0; e < 4; ++e) {
          o[e] = (short)f2bf(u0[e]); o[4 + e] = (short)f2bf(u1[e]);
          ps[e] += u0[e]; ps[4 + e] += u1[e];
        }
        af[kc][mi] = o;
      }
      // column sum over 48 rows: butterfly over the 16 lr lanes (result dup'd over lr)
      s16x8 st8;
#pragma unroll
      for (int e = 0; e < 8; ++e) {
        ps[e] = redsum_lr(ps[e]);
        st8[e] = (short)f2bf(ps[e]);
      }
      af[kc][3] = st8;
      if (lr == 0) {
        const int d0 = kc * 32 + lk * 8;
        *(f32x4*)(ST + (size_t)b * 256 + d0) = (f32x4){ps[0], ps[1], ps[2], ps[3]};
        *(f32x4*)(ST + (size_t)b * 256 + d0 + 4) = (f32x4){ps[4], ps[5], ps[6], ps[7]};
        u16x8 sh;
#pragma unroll
        for (int e = 0; e < 8; ++e) sh[e] = (u16)st8[e];
        *(u16x8*)(GS + (size_t)b * 512 + 256 + d0) = sh;
      }
    }
  } else {
    // ---- A from X (bf16 row-major) ----
#pragma unroll
    for (int kc = 0; kc < 8; ++kc)
#pragma unroll
      for (int mi = 0; mi < 3; ++mi)
        af[kc][mi] = *(const s16x8*)(Xg + (size_t)(mi * 16 + lr) * 256 + kc * 32 + lk * 8);

    if (GRUF) {
      const float* g1 = G1 + (size_t)b * 768;
      const float* g2 = G2 + (size_t)b * 768;
      const int d0 = l * 4;
      f32x4 xz = *(const f32x4*)(g1 + d0);
      f32x4 xr = *(const f32x4*)(g1 + 256 + d0);
      f32x4 xh = *(const f32x4*)(g1 + 512 + d0);
      f32x4 hz = *(const f32x4*)(g2 + d0);
      f32x4 hr = *(const f32x4*)(g2 + 256 + d0);
      f32x4 hh = *(const f32x4*)(g2 + 512 + d0);
      f32x4 bxz = *(const f32x4*)(bx + d0);
      f32x4 bxr = *(const f32x4*)(bx + 256 + d0);
      f32x4 bxh = *(const f32x4*)(bx + 512 + d0);
      f32x4 bhz = *(const f32x4*)(bh + d0);
      f32x4 bhr = *(const f32x4*)(bh + 256 + d0);
      f32x4 bhh = *(const f32x4*)(bh + 512 + d0);
      f32x4 h0 = *(const f32x4*)(ST + (size_t)b * 256 + d0);
      f32x4 sn;
      u16x4 snh;
#pragma unroll
      for (int j = 0; j < 4; ++j) {
        float z = sigm(xz[j] + bxz[j] + hz[j] + bhz[j]);
        float r = sigm(xr[j] + bxr[j] + hr[j] + bhr[j]);
        float n = tanhf(xh[j] + bxh[j] + r * (hh[j] + bhh[j]));
        sn[j] = z * h0[j] + (1.f - z) * n;
        snh[j] = f2bf(sn[j]);
      }
      *(f32x4*)(ST + (size_t)b * 256 + d0) = sn;          // state_t f32
      *(u16x4*)(GS + (size_t)b * 512 + 256 + d0) = snh;   // state_t bf16 (gates kernel)
      *(u16x4*)(&stH[w][d0]) = snh;                       // LDS for A-fragment build
      asm volatile("s_waitcnt lgkmcnt(0)" ::: "memory");
#pragma unroll
      for (int kc = 0; kc < 8; ++kc)
        af[kc][3] = *(const s16x8*)&stH[w][kc * 32 + lk * 8];
    } else {
#pragma unroll
      for (int kc = 0; kc < 8; ++kc)
        af[kc][3] = *(const s16x8*)(Sg + kc * 32 + lk * 8);
    }
  }

  s16x8 be[8];
#pragma unroll
  for (int kc = 0; kc < 8; ++kc)
    be[kc] = *(const s16x8*)(EP + ((size_t)kc * 64 + l) * 8);

  asm volatile("s_waitcnt vmcnt(0)" ::: "memory");  // vmcnt domain now stage/store-only
  STAGE(8, 0)  // first processed strip: Ws window 0 (BP strip 8)

  // ---- E-phase: 32 MFMA -> e_src (rows 0-47, cols 0-7) + e_dst (cols 8-15) ----
  {
    f32x4 ae[4];
#pragma unroll
    for (int mi = 0; mi < 4; ++mi) ae[mi] = (f32x4){0.f, 0.f, 0.f, 0.f};
#pragma unroll
    for (int kc = 0; kc < 8; ++kc)
#pragma unroll
      for (int mi = 0; mi < 4; ++mi)
        ae[mi] = __builtin_amdgcn_mfma_f32_16x16x32_bf16(af[kc][mi], be[kc], ae[mi], 0, 0, 0);

    // e_dst[h] lives on lane (lr'=8+h) as ae[3][*] (all rows equal).
    const float edv = __shfl(ae[3][0], 8 + lr);  // valid for lanes lr<8

    if (lr < 8) {  // lane lr owns head lr for its lk-row-group
      float ev[3][4];
      float m = -1e30f;
#pragma unroll
      for (int mi = 0; mi < 3; ++mi)
#pragma unroll
        for (int j = 0; j < 4; ++j) {
          float v = ae[mi][j] + edv;
          v = (v > 0.f) ? v : NEG_SLOPE * v;  // leaky_relu
          ev[mi][j] = v;
          m = fmaxf(m, v);
        }
      m = redmax_lk(m);  // max over all 48 nodes
      float sm = 0.f;
#pragma unroll
      for (int mi = 0; mi < 3; ++mi)
#pragma unroll
        for (int j = 0; j < 4; ++j) {
          float ex = expf(ev[mi][j] - m);
          ev[mi][j] = ex; sm += ex;
        }
      sm = redsum_lk(sm);
      const float inv = 1.f / sm;
#pragma unroll
      for (int mi = 0; mi < 3; ++mi)
#pragma unroll
        for (int j = 0; j < 4; ++j)
          alphaL[w][lr][mi * 16 + lk * 4 + j] = ev[mi][j] * inv;
    }
  }

  f32x2 svA[8];  // sv pairs (cols 2lr, 2lr+1 of each head window), from Ws mi=3

  // ---- strip pipeline: Ws strips (f=0..7, BP 8..15) then Wg strips (f=8..15, BP 0..7) ----
#pragma unroll
  for (int f = 0; f < 16; ++f) {
    if (f == 0)       { asm volatile("s_waitcnt vmcnt(0)" ::: "memory"); }
    else if (f <= 8)  {
      if (LAST)       { asm volatile("s_waitcnt vmcnt(0)" ::: "memory"); }
      else            { asm volatile("s_waitcnt vmcnt(12)" ::: "memory"); }
    } else            { asm volatile("s_waitcnt vmcnt(1)" ::: "memory"); }
    __builtin_amdgcn_s_barrier();
    if (f + 1 < 16) {
      const int ns = (f + 1 < 8) ? (9 + f) : (f + 1 - 8);
      STAGE(ns, (f + 1) & 1)
    }

    const u16* bufB = ldsB[f & 1];

    if (f < 8) {
      // ---- Ws window u=f: x@Ws (mi 0-2, skipped in LAST) + sv (mi 3) ----
      f32x4 acc[4][2];
#pragma unroll
      for (int mi = 0; mi < 4; ++mi)
#pragma unroll
        for (int ni = 0; ni < 2; ++ni) acc[mi][ni] = (f32x4){0.f, 0.f, 0.f, 0.f};
#pragma unroll
      for (int kc = 0; kc < 8; ++kc) {
        s16x8 bfr[2];
#pragma unroll
        for (int ni = 0; ni < 2; ++ni)
          bfr[ni] = *(const s16x8*)&bufB[((kc * 2 + ni) * 64 + l) * 8];
        if (!LAST) {
#pragma unroll
          for (int mi = 0; mi < 3; ++mi)
#pragma unroll
            for (int ni = 0; ni < 2; ++ni)
              acc[mi][ni] = __builtin_amdgcn_mfma_f32_16x16x32_bf16(
                  af[kc][mi], bfr[ni], acc[mi][ni], 0, 0, 0);
        }
#pragma unroll
        for (int ni = 0; ni < 2; ++ni)
          acc[3][ni] = __builtin_amdgcn_mfma_f32_16x16x32_bf16(
              af[kc][3], bfr[ni], acc[3][ni], 0, 0, 0);
      }
      svA[f] = (f32x2){acc[3][0][0], acc[3][1][0]};  // sv (rows all equal)
      if (!LAST) {
#pragma unroll
        for (int mi = 0; mi < 3; ++mi)
#pragma unroll
          for (int j = 0; j < 4; ++j) {
            u16x2 o = {f2bf(fmaxf(acc[mi][0][j], 0.f)),
                       f2bf(fmaxf(acc[mi][1][j], 0.f))};
            *(u16x2*)(Xn + (size_t)(b * 48 + mi * 16 + lk * 4 + j) * 256 +
                      f * 32 + 2 * lr) = o;
          }
      }
    } else {
      // ---- Wg head h=f-8: msg via alpha table, g0 = relu(msg+sv), 1 u16x2 store ----
      const int h = f - 8;
      f32x4 acc[3][2];
#pragma unroll
      for (int mi = 0; mi < 3; ++mi)
#pragma unroll
        for (int ni = 0; ni < 2; ++ni) acc[mi][ni] = (f32x4){0.f, 0.f, 0.f, 0.f};
#pragma unroll
      for (int kc = 0; kc < 8; ++kc) {
        s16x8 bfr[2];
#pragma unroll
        for (int ni = 0; ni < 2; ++ni)
          bfr[ni] = *(const s16x8*)&bufB[((kc * 2 + ni) * 64 + l) * 8];
#pragma unroll
        for (int mi = 0; mi < 3; ++mi)
#pragma unroll
          for (int ni = 0; ni < 2; ++ni)
            acc[mi][ni] = __builtin_amdgcn_mfma_f32_16x16x32_bf16(
                af[kc][mi], bfr[ni], acc[mi][ni], 0, 0, 0);
      }
      float mmE = 0.f, mmO = 0.f;
#pragma unroll
      for (int mi = 0; mi < 3; ++mi)
#pragma unroll
        for (int j = 0; j < 4; ++j) {
          const float a = alphaL[w][h][mi * 16 + lk * 4 + j];
          mmE += a * acc[mi][0][j];
          mmO += a * acc[mi][1][j];
        }
      mmE = redsum_lk(mmE);
      mmO = redsum_lk(mmO);
      if (lk == 0) {
        u16x2 o = {f2bf(fmaxf(mmE + svA[h][0], 0.f)),
                   f2bf(fmaxf(mmO + svA[h][1], 0.f))};
        *(u16x2*)(GS + (size_t)b * 512 + h * 32 + 2 * lr) = o;
      }
    }
  }
#undef STAGE
}

// ---------------------------------------------------------------------------
// Generic bf16 GEMM: C[M,N] = A[M,K=256] * Bt[N,K=256]^T, 128x128, pipelined.
// EPI 2 = f32 + bias (projection).
// ---------------------------------------------------------------------------
template<int EPI>
__global__ __launch_bounds__(256)
void gemm_bt(const u16* __restrict__ A, int lda,
             const u16* __restrict__ Bt,
             float* __restrict__ Cf, int ldc, const float* __restrict__ bias) {
  __shared__ u16 ldsA[2][2 * 128 * 32];
  __shared__ u16 ldsB[2][2 * 128 * 32];
  const int tid = threadIdx.x;
  const int w = tid >> 6, l = tid & 63;
  const int wr = w >> 1, wc = w & 1;
  const int lr = l & 15, lk = l >> 4;
  const int sxor = (lr >> 1) & 3;
  const int m0 = blockIdx.x * 128, n0 = blockIdx.y * 128;

#define STAGE_AB(KT, BUF)                                                      \
  {                                                                            \
    const u16* Ag = A + (size_t)m0 * lda + (KT)*64;                            \
    const u16* Bg = Bt + (size_t)n0 * 256 + (KT)*64;                           \
    _Pragma("unroll") for (int i = 0; i < 4; ++i) {                            \
      int q = i * 256 + tid;                                                   \
      int h2 = q >> 9, r = (q >> 2) & 127, c4 = q & 3;                         \
      int c4s = c4 ^ ((r >> 1) & 3);                                           \
      gload_lds16(Ag + (size_t)r * lda + h2 * 32 + c4s * 8,                    \
                  &ldsA[BUF][(i * 256 + w * 64) * 8]);                         \
      gload_lds16(Bg + (size_t)r * 256 + h2 * 32 + c4s * 8,                    \
                  &ldsB[BUF][(i * 256 + w * 64) * 8]);                         \
    }                                                                          \
  }

  f32x4 acc[4][4];
#pragma unroll
  for (int i = 0; i < 4; ++i)
#pragma unroll
    for (int j = 0; j < 4; ++j) acc[i][j] = (f32x4){0.f, 0.f, 0.f, 0.f};

  STAGE_AB(0, 0)
#pragma unroll
  for (int kt = 0; kt < 4; ++kt) {
    __syncthreads();
    if (kt < 3) STAGE_AB(kt + 1, (kt + 1) & 1)
    const u16* bA = ldsA[kt & 1];
    const u16* bB = ldsB[kt & 1];
#pragma unroll
    for (int hh = 0; hh < 2; ++hh) {
      s16x8 af[4], bfr[4];
#pragma unroll
      for (int mi = 0; mi < 4; ++mi)
        af[mi] = *(const s16x8*)&bA[(hh * 128 + wr * 64 + mi * 16 + lr) * 32 +
                                    (lk ^ sxor) * 8];
#pragma unroll
      for (int ni = 0; ni < 4; ++ni)
        bfr[ni] = *(const s16x8*)&bB[(hh * 128 + wc * 64 + ni * 16 + lr) * 32 +
                                     (lk ^ sxor) * 8];
#pragma unroll
      for (int mi = 0; mi < 4; ++mi)
#pragma unroll
        for (int ni = 0; ni < 4; ++ni)
          acc[mi][ni] = __builtin_amdgcn_mfma_f32_16x16x32_bf16(af[mi], bfr[ni],
                                                                acc[mi][ni], 0, 0, 0);
    }
  }
#undef STAGE_AB

#pragma unroll
  for (int mi = 0; mi < 4; ++mi) {
#pragma unroll
    for (int ni = 0; ni < 4; ++ni) {
      f32x4 v = acc[mi][ni];
      int r = m0 + wr * 64 + mi * 16 + lk * 4;
      int c = n0 + wc * 64 + ni * 16 + lr;
#pragma unroll
      for (int j = 0; j < 4; ++j) {
        float fv = v[j];
        if (EPI == 0) Cf[(size_t)(r + j) * ldc + c] = fv;
        else          Cf[(size_t)(r + j) * ldc + c] = fv + bias[c];
      }
    }
  }
}

// Merged GRU-gate GEMM: blockIdx.y<6 -> G1 = g0@wx ; else G2 = state@wh. Pipelined.
__global__ __launch_bounds__(256)
void gemm_gates(const u16* __restrict__ GS, const u16* __restrict__ WXT,
                const u16* __restrict__ WHT, float* __restrict__ G1,
                float* __restrict__ G2) {
  __shared__ u16 ldsA[2][2 * 128 * 32];
  __shared__ u16 ldsB[2][2 * 128 * 32];
  const bool second = blockIdx.y >= 6;
  const u16* A = GS + (second ? 256 : 0);
  const u16* Bt = second ? WHT : WXT;
  float* Cf = second ? G2 : G1;
  const int n0 = (second ? blockIdx.y - 6 : blockIdx.y) * 128;
  const int m0 = blockIdx.x * 128;
  const int tid = threadIdx.x;
  const int w = tid >> 6, l = tid & 63;
  const int wr = w >> 1, wc = w & 1;
  const int lr = l & 15, lk = l >> 4;
  const int sxor = (lr >> 1) & 3;

#define STAGE_AB(KT, BUF)                                                      \
  {                                                                            \
    const u16* Ag = A + (size_t)m0 * 512 + (KT)*64;                            \
    const u16* Bg = Bt + (size_t)n0 * 256 + (KT)*64;                           \
    _Pragma("unroll") for (int i = 0; i < 4; ++i) {                            \
      int q = i * 256 + tid;                                                   \
      int h2 = q >> 9, r = (q >> 2) & 127, c4 = q & 3;                         \
      int c4s = c4 ^ ((r >> 1) & 3);                                           \
      gload_lds16(Ag + (size_t)r * 512 + h2 * 32 + c4s * 8,                    \
                  &ldsA[BUF][(i * 256 + w * 64) * 8]);                         \
      gload_lds16(Bg + (size_t)r * 256 + h2 * 32 + c4s * 8,                    \
                  &ldsB[BUF][(i * 256 + w * 64) * 8]);                         \
    }                                                                          \
  }

  f32x4 acc[4][4];
#pragma unroll
  for (int i = 0; i < 4; ++i)
#pragma unroll
    for (int j = 0; j < 4; ++j) acc[i][j] = (f32x4){0.f, 0.f, 0.f, 0.f};

  STAGE_AB(0, 0)
#pragma unroll
  for (int kt = 0; kt < 4; ++kt) {
    __syncthreads();
    if (kt < 3) STAGE_AB(kt + 1, (kt + 1) & 1)
    const u16* bA = ldsA[kt & 1];
    const u16* bB = ldsB[kt & 1];
#pragma unroll
    for (int hh = 0; hh < 2; ++hh) {
      s16x8 af[4], bfr[4];
#pragma unroll
      for (int mi = 0; mi < 4; ++mi)
        af[mi] = *(const s16x8*)&bA[(hh * 128 + wr * 64 + mi * 16 + lr) * 32 +
                                    (lk ^ sxor) * 8];
#pragma unroll
      for (int ni = 0; ni < 4; ++ni)
        bfr[ni] = *(const s16x8*)&bB[(hh * 128 + wc * 64 + ni * 16 + lr) * 32 +
                                     (lk ^ sxor) * 8];
#pragma unroll
      for (int mi = 0; mi < 4; ++mi)
#pragma unroll
        for (int ni = 0; ni < 4; ++ni)
          acc[mi][ni] = __builtin_amdgcn_mfma_f32_16x16x32_bf16(af[mi], bfr[ni],
                                                                acc[mi][ni], 0, 0, 0);
    }
  }
#undef STAGE_AB

#pragma unroll
  for (int mi = 0; mi < 4; ++mi) {
#pragma unroll
    for (int ni = 0; ni < 4; ++ni) {
      f32x4 v = acc[mi][ni];
      int r = m0 + wr * 64 + mi * 16 + lk * 4;
      int c = n0 + wc * 64 + ni * 16 + lr;
#pragma unroll
      for (int j = 0; j < 4; ++j)
        Cf[(size_t)(r + j) * 768 + c] = v[j];
    }
  }
}

// GRU elementwise (final step only: state_4 for projection)
__global__ void gru_kernel(const float* __restrict__ G1, const float* __restrict__ G2,
                           const float* __restrict__ bx, const float* __restrict__ bh,
                           float* __restrict__ state, u16* __restrict__ GS) {
  const int b = blockIdx.x, d = threadIdx.x;
  const float* g1 = G1 + (size_t)b * 768;
  const float* g2 = G2 + (size_t)b * 768;
  float xz = g1[d] + bx[d], xr = g1[256 + d] + bx[256 + d], xh = g1[512 + d] + bx[512 + d];
  float hz = g2[d] + bh[d], hr = g2[256 + d] + bh[256 + d], hh2 = g2[512 + d] + bh[512 + d];
  float z = sigm(xz + hz);
  float r = sigm(xr + hr);
  float n = tanhf(xh + r * hh2);
  float h0 = state[b * 256 + d];
  float sn = z * h0 + (1.f - z) * n;
  state[b * 256 + d] = sn;
  GS[(size_t)b * 512 + 256 + d] = f2bf(sn);
}

extern "C" void kernel_launch(void* const* d_in, const int* in_sizes, int n_in,
                              void* d_out, int out_size, void* d_ws, size_t ws_size,
                              hipStream_t stream) {
  const float* nf  = (const float*)d_in[0];
  const float* Wg  = (const float*)d_in[2];
  const float* Ws  = (const float*)d_in[3];
  const float* asr = (const float*)d_in[4];
  const float* ads = (const float*)d_in[5];
  const float* wx  = (const float*)d_in[6];
  const float* wh  = (const float*)d_in[7];
  const float* bx  = (const float*)d_in[8];
  const float* bh  = (const float*)d_in[9];
  const float* pw  = (const float*)d_in[10];
  const float* pb  = (const float*)d_in[11];
  float* out = (float*)d_out;

  char* p = (char*)d_ws;
  size_t off = 0;
  auto alloc = [&](size_t bytes) { char* r = p + off; off += (bytes + 255) & ~255ULL; return r; };
  u16* WXT   = (u16*)alloc(768 * 256 * 2);
  u16* WHT   = (u16*)alloc(768 * 256 * 2);
  u16* PRJ   = (u16*)alloc(256 * 256 * 2);
  u16* BP    = (u16*)alloc(512 * 256 * 2);            // [Wg|Ws] 32-col strip pack
  u16* EP    = (u16*)alloc(512 * 8 * 2);              // [WGAS|WGAD] fragment pack
  u16* X0    = (u16*)alloc((size_t)98304 * 256 * 2);  // x buffers (row-major bf16)
  u16* X1    = (u16*)alloc((size_t)98304 * 256 * 2);
  float* G1   = (float*)alloc((size_t)2048 * 768 * 4);
  float* G2   = (float*)alloc((size_t)2048 * 768 * 4);
  u16* GS     = (u16*)alloc((size_t)2048 * 512 * 2);  // [g0 | state] bf16
  float* ST   = (float*)alloc((size_t)2048 * 256 * 4);

  // setup: weight packing only (prep is folded into fused t=0)
  setup_kernel<<<192, 256, 0, stream>>>(Wg, Ws, wx, wh, pw, asr, ads,
                                        WXT, WHT, PRJ, BP, EP);

  // t=0: A from nf (f32), state_0 computed in-register
  fused_step<false, false, true><<<1024, 128, 0, stream>>>(
      nullptr, nf, BP, EP, GS, X0, G1, G2, bx, bh, ST);
  gemm_gates<<<dim3(16, 12), 256, 0, stream>>>(GS, WXT, WHT, G1, G2);
  // t=1
  fused_step<true, false, false><<<1024, 128, 0, stream>>>(
      X0, nullptr, BP, EP, GS, X1, G1, G2, bx, bh, ST);
  gemm_gates<<<dim3(16, 12), 256, 0, stream>>>(GS, WXT, WHT, G1, G2);
  // t=2
  fused_step<true, false, false><<<1024, 128, 0, stream>>>(
      X1, nullptr, BP, EP, GS, X0, G1, G2, bx, bh, ST);
  gemm_gates<<<dim3(16, 12), 256, 0, stream>>>(GS, WXT, WHT, G1, G2);
  // t=3 (LAST: Ws strips compute only sv; no Xn)
  fused_step<true, true, false><<<1024, 128, 0, stream>>>(
      X0, nullptr, BP, EP, GS, nullptr, G1, G2, bx, bh, ST);
  gemm_gates<<<dim3(16, 12), 256, 0, stream>>>(GS, WXT, WHT, G1, G2);
  // final GRU -> state_4, then projection
  gru_kernel<<<2048, 256, 0, stream>>>(G1, G2, bx, bh, ST, GS);
  gemm_bt<2><<<dim3(16, 2), 256, 0, stream>>>(GS + 256, 512, PRJ, out, 256, pb);
}